// Round 8
// baseline (183.080 us; speedup 1.0000x reference)
//
#include <hip/hip_runtime.h>
#include <hip/hip_bf16.h>

typedef unsigned short ushort_t;
typedef unsigned int uint_t;
typedef __attribute__((ext_vector_type(8))) short v8s;   // 8 x bf16 (4 VGPRs)
typedef __attribute__((ext_vector_type(4))) float v4f;   // MFMA accumulator / float4

#define BN_SCALE 0.9999950000374997f

__device__ __forceinline__ ushort_t f2bf(float f) {
    union { uint_t i; float f; } v;
    v.f = f;
    uint_t b = v.i;
    b += 0x7fffu + ((b >> 16) & 1u);   // RNE
    return (ushort_t)(b >> 16);
}

// packed bf16 convert: v_cvt_pk_bf16_f32 (RNE). Low ushort = first arg.
__device__ __forceinline__ uint_t pkbf(float a, float b) {
    union { __hip_bfloat162 h2; uint_t u; } t;
    float2 f; f.x = a; f.y = b;
    t.h2 = __float22bfloat162_rn(f);
    return t.u;
}

// 8 x f32 -> v8s via 4 cvt_pk
__device__ __forceinline__ v8s cvt8f(const float* __restrict__ p) {
    const v4f a = *(const v4f*)p;
    const v4f b = *(const v4f*)(p + 4);
    union { uint4 q; v8s s; } r;
    r.q = make_uint4(pkbf(a[0], a[1]), pkbf(a[2], a[3]),
                     pkbf(b[0], b[1]), pkbf(b[2], b[3]));
    return r.s;
}

// ---------------------------------------------------------------------------
// Kernel 1: cur{0,1}[n][d] = src_feats[n] . fc{0,1}_w[d] + fc{0,1}_b[d]
// Pure-MFMA GEMM; fc weights converted in-register from f32 (cvt8f, cheap).
// 128 rows/block (2 groups of 64), weights loaded once per block.
// SWAPPED operands: acc = mfma(w, feat) -> C^T: row=(quad,reg)=d, col=lane=n.
// Blocks [CURB, CURB+80): folded weight-conversion (out_w/m0_w/m1_w f32->bf16)
// ---------------------------------------------------------------------------
__global__ __launch_bounds__(256) void cur_conv_kernel(
    const float* __restrict__ src_feats,                     // (N,64) f32
    const float* __restrict__ fc0_w, const float* __restrict__ fc0_b,
    const float* __restrict__ fc1_w, const float* __restrict__ fc1_b,
    ushort_t* __restrict__ cur0, ushort_t* __restrict__ cur1,
    const float* __restrict__ out_w, ushort_t* __restrict__ out_wb,
    const float* __restrict__ m0_w,  ushort_t* __restrict__ m0_wb,
    const float* __restrict__ m1_w,  ushort_t* __restrict__ m1_wb,
    const int CURB)
{
    if (blockIdx.x >= CURB) {
        // ---- weight conversion tail: 80 blocks ----
        const int b = blockIdx.x - CURB;
        const float* src;
        ushort_t* dst;
        int base;
        if (b < 64)      { src = out_w; dst = out_wb; base = b; }
        else if (b < 72) { src = m0_w;  dst = m0_wb;  base = b - 64; }
        else             { src = m1_w;  dst = m1_wb;  base = b - 72; }
        const int i = (base * 256 + threadIdx.x) * 4;
        const v4f v = *(const v4f*)(src + i);
        *(uint2*)(dst + i) = make_uint2(pkbf(v[0], v[1]), pkbf(v[2], v[3]));
        return;
    }

    const int tid  = threadIdx.x;
    const int lane = tid & 63;
    const int wid  = tid >> 6;
    const int col  = lane & 15;
    const int quad = lane >> 4;
    const int row0 = blockIdx.x * 128 + wid * 16;

    // ---- weight fragments (cvt from f32) + bias4: once, reused both groups ----
    v8s bfrag[8][2];
    v4f bias4[8];
    #pragma unroll
    for (int ct = 0; ct < 8; ++ct) {
        const int d = (ct & 3) * 16 + col;            // operand outer (lane&15)
        const float* w = (ct < 4 ? fc0_w : fc1_w) + d * 64;
        bias4[ct] = *(const v4f*)((ct < 4 ? fc0_b : fc1_b) + (ct & 3) * 16 + quad * 4);
        #pragma unroll
        for (int kf = 0; kf < 2; ++kf)
            bfrag[ct][kf] = cvt8f(w + kf * 32 + quad * 8);
    }

    #pragma unroll
    for (int g = 0; g < 2; ++g) {
        const int rows = row0 + g * 64;
        const int n    = rows + col;

        v8s afrag[2];
        #pragma unroll
        for (int kf = 0; kf < 2; ++kf)
            afrag[kf] = cvt8f(src_feats + (size_t)n * 64 + kf * 32 + quad * 8);

        v4f acc[8];
        #pragma unroll
        for (int ct = 0; ct < 8; ++ct)
            acc[ct] = bias4[ct];                      // bias[d], d=(ct&3)*16+quad*4+r

        #pragma unroll
        for (int kf = 0; kf < 2; ++kf)
            #pragma unroll
            for (int ct = 0; ct < 8; ++ct)
                acc[ct] = __builtin_amdgcn_mfma_f32_16x16x32_bf16(
                    bfrag[ct][kf], afrag[kf], acc[ct], 0, 0, 0);   // swapped: C^T

        #pragma unroll
        for (int ct = 0; ct < 8; ++ct) {
            ushort_t* dst = (ct < 4) ? cur0 : cur1;
            const uint2 u = make_uint2(pkbf(acc[ct][0], acc[ct][1]),
                                       pkbf(acc[ct][2], acc[ct][3]));
            *(uint2*)(dst + (size_t)n * 64 + (ct & 3) * 16 + quad * 4) = u;
        }
    }
}

// ---------------------------------------------------------------------------
// SA layer body (R6 text, verbatim — measured 43.6 us, PASS). 128 pairs/block.
// Phase A: paired-d SCALAR math (packed variants abandoned: R1/R2/R7 failures);
// block-uniform empty skip. Phase B: per-wave col-split over MB m's.
// ---------------------------------------------------------------------------
template <int S>
__device__ __forceinline__ void sa_body(
    const int bid,
    const float* __restrict__ src_xyz,   // (N,3) f32
    const float* __restrict__ dst_xyz,   // (M,3) f32
    const int*   __restrict__ idx,       // (M,S)
    const int*   __restrict__ empty,     // (M,)
    const float* __restrict__ p_w,       // (64,6)
    const float* __restrict__ p_g,
    const float* __restrict__ p_b,
    const ushort_t* __restrict__ m_wb,   // (128,64) bf16 (pre-converted)
    const float* __restrict__ m_g,
    const float* __restrict__ m_b,
    const ushort_t* __restrict__ cur,    // (N,64) bf16
    ushort_t*    __restrict__ f01,       // (M,256) bf16
    const int layer_off,
    ushort_t* xlds,                      // [128 * 72]
    v4f*      flds)                      // [128]
{
    constexpr int PAIRS = 128;
    constexpr int MB = PAIRS / S;        // 4 (S=32) or 8 (S=16)
    constexpr int XP = 72;               // padded row stride (ushorts), 144 B
    constexpr int T  = S / 4;            // pairs per (wave, mi) in phase A

    const int tid  = threadIdx.x;
    const int lane = tid & 63;
    const int wid  = tid >> 6;           // 0..3
    const int m0   = bid * MB;

    // ---- prologue 1: cur rows -> xlds (coalesced, in-place with x) ----
    {
        const int p  = tid >> 1;         // pair 0..127
        const int hf = tid & 1;
        const int m  = m0 + p / S;
        const int i  = idx[(size_t)m * S + (p & (S - 1))];
        const uint_t* crow = (const uint_t*)(cur + (size_t)i * 64) + hf * 16;
        const uint4 c0 = *(const uint4*)(crow + 0);
        const uint4 c1 = *(const uint4*)(crow + 4);
        const uint4 c2 = *(const uint4*)(crow + 8);
        const uint4 c3 = *(const uint4*)(crow + 12);
        uint_t* drow = (uint_t*)(xlds + p * XP) + hf * 16;
        *(uint4*)(drow + 0)  = c0;
        *(uint4*)(drow + 4)  = c1;
        *(uint4*)(drow + 8)  = c2;
        *(uint4*)(drow + 12) = c3;
    }
    // ---- prologue 2: relative coords -> flds ----
    if (tid < PAIRS) {
        const int p = tid;
        const int m = m0 + p / S;
        const int i = idx[(size_t)m * S + (p & (S - 1))];
        const float dx = dst_xyz[m * 3 + 0];
        const float dy = dst_xyz[m * 3 + 1];
        const float dz = dst_xyz[m * 3 + 2];
        v4f r;
        r[0] = src_xyz[i * 3 + 0] - dx;
        r[1] = src_xyz[i * 3 + 1] - dy;
        r[2] = src_xyz[i * 3 + 2] - dz;
        r[3] = 0.0f;
        flds[p] = r;
    }

    // ---- per-lane paired-d constants (d = dd, dd+1) ----
    const int dd = (lane & 31) * 2;
    const int psub = lane >> 5;          // 0/1: which pair of the iter
    const float pgA = p_g[dd] * BN_SCALE;
    const float pgB = p_g[dd + 1] * BN_SCALE;
    const float pbA = p_b[dd];
    const float pbB = p_b[dd + 1];
    const float pwA0 = p_w[dd * 6 + 0] * pgA;
    const float pwA1 = p_w[dd * 6 + 1] * pgA;
    const float pwA2 = p_w[dd * 6 + 2] * pgA;
    const float pdA0 = p_w[dd * 6 + 3] * pgA;
    const float pdA1 = p_w[dd * 6 + 4] * pgA;
    const float pdA2 = p_w[dd * 6 + 5] * pgA;
    const float pwB0 = p_w[dd * 6 + 6] * pgB;
    const float pwB1 = p_w[dd * 6 + 7] * pgB;
    const float pwB2 = p_w[dd * 6 + 8] * pgB;
    const float pdB0 = p_w[dd * 6 + 9] * pgB;
    const float pdB1 = p_w[dd * 6 + 10] * pgB;
    const float pdB2 = p_w[dd * 6 + 11] * pgB;

    __syncthreads();

    // ================= phase A: paired-d, pure LDS + VALU =================
    const int tbase = wid * T;
    #pragma unroll
    for (int mi = 0; mi < MB; ++mi) {
        const int m = m0 + mi;                        // uniform
        const int em = empty[m];                      // uniform -> s_cbranch
        if (em) {
            // x must be exactly 0 for empty dst points (same word coverage)
            #pragma unroll
            for (int it = 0; it < T / 2; ++it) {
                const int p = mi * S + tbase + it * 2 + psub;
                *(uint_t*)(xlds + p * XP + dd) = 0u;
            }
        } else {
            const float dx = dst_xyz[m * 3 + 0];      // uniform loads
            const float dy = dst_xyz[m * 3 + 1];
            const float dz = dst_xyz[m * 3 + 2];
            const float vbA = fmaf(pdA0, dx, fmaf(pdA1, dy, fmaf(pdA2, dz, pbA)));
            const float vbB = fmaf(pdB0, dx, fmaf(pdB1, dy, fmaf(pdB2, dz, pbB)));

            #pragma unroll
            for (int it = 0; it < T / 2; ++it) {
                const int p = mi * S + tbase + it * 2 + psub;
                const v4f r = flds[p];                    // 2-addr broadcast b128
                const uint_t cu = *(const uint_t*)(xlds + p * XP + dd);   // b32
                const float c0 = __uint_as_float(cu << 16);
                const float c1 = __uint_as_float(cu & 0xffff0000u);

                const float v0 = fmaf(pwA0, r[0], fmaf(pwA1, r[1], fmaf(pwA2, r[2], vbA)));
                const float v1 = fmaf(pwB0, r[0], fmaf(pwB1, r[1], fmaf(pwB2, r[2], vbB)));
                const float rc0 = __builtin_amdgcn_rcpf(1.0f + __expf(-v0));
                const float rc1 = __builtin_amdgcn_rcpf(1.0f + __expf(-v1));
                const float x0 = fmaf(v0, rc0, c0);
                const float x1 = fmaf(v1, rc1, c1);

                *(uint_t*)(xlds + p * XP + dd) = pkbf(x0, x1);  // b32 in place
            }
        }
    }

    // ---- phase-B per-wave constants (direct bf16 loads, no cvt) ----
    const int col  = lane & 15;
    const int quad = lane >> 4;
    v8s bfrag[2][2];                     // [ct][kf]
    float mgv[2], mbv[2];
    #pragma unroll
    for (int c = 0; c < 2; ++c) {
        const int h = (wid * 2 + c) * 16 + col;
        #pragma unroll
        for (int kf = 0; kf < 2; ++kf)
            bfrag[c][kf] = *(const v8s*)(m_wb + h * 64 + kf * 32 + quad * 8);
        mgv[c] = m_g[h] * BN_SCALE;
        mbv[c] = m_b[h];
    }

    __syncthreads();

    // ================= phase B: MB independent m's per wave =================
    #pragma unroll
    for (int mi = 0; mi < MB; ++mi) {
        const int m = m0 + mi;
        v4f acc[S / 16][2];
        #pragma unroll
        for (int rt = 0; rt < S / 16; ++rt)
            #pragma unroll
            for (int c = 0; c < 2; ++c)
                acc[rt][c] = (v4f)0.0f;

        #pragma unroll
        for (int rt = 0; rt < S / 16; ++rt) {
            #pragma unroll
            for (int kf = 0; kf < 2; ++kf) {
                const v8s afrag = *(const v8s*)(
                    xlds + ((mi * S + rt * 16 + col)) * XP + kf * 32 + quad * 8);
                acc[rt][0] = __builtin_amdgcn_mfma_f32_16x16x32_bf16(
                    afrag, bfrag[0][kf], acc[rt][0], 0, 0, 0);
                acc[rt][1] = __builtin_amdgcn_mfma_f32_16x16x32_bf16(
                    afrag, bfrag[1][kf], acc[rt][1], 0, 0, 0);
            }
        }

        // epilogue: bn, relu, max over s (C/D layout: col=lane&15, row=quad*4+r)
        float vmax0 = 0.0f, vmax1 = 0.0f;
        #pragma unroll
        for (int c = 0; c < 2; ++c) {
            float vm = 0.0f;   // relu(y)>=0, so 0 is a valid identity
            #pragma unroll
            for (int rt = 0; rt < S / 16; ++rt)
                #pragma unroll
                for (int r = 0; r < 4; ++r) {
                    const float y = fmaf(acc[rt][c][r], mgv[c], mbv[c]);
                    vm = fmaxf(vm, y);
                }
            vm = fmaxf(vm, __shfl_xor(vm, 16));
            vm = fmaxf(vm, __shfl_xor(vm, 32));
            if (c == 0) vmax0 = vm; else vmax1 = vm;
        }
        if (lane < 32) {
            const int c = lane >> 4;
            const float val = (c == 0) ? vmax0 : vmax1;
            f01[m * 256 + layer_off + (wid * 2 + c) * 16 + (lane & 15)] = f2bf(val);
        }
    }
}

// ---------------------------------------------------------------------------
// Kernel 2: fused SA layers. Blocks [0, G32) run layer 1 (S=32), blocks
// [G32, G32+G16) run layer 0 (S=16).
// ---------------------------------------------------------------------------
__global__ __launch_bounds__(256, 6) void sa_fused_kernel(
    const float* __restrict__ src_xyz, const float* __restrict__ dst_xyz,
    const int* __restrict__ idx0, const int* __restrict__ empty0,
    const float* __restrict__ p0_w, const float* __restrict__ p0_g, const float* __restrict__ p0_b,
    const ushort_t* __restrict__ m0_wb, const float* __restrict__ m0_g, const float* __restrict__ m0_b,
    const ushort_t* __restrict__ cur0,
    const int* __restrict__ idx1, const int* __restrict__ empty1,
    const float* __restrict__ p1_w, const float* __restrict__ p1_g, const float* __restrict__ p1_b,
    const ushort_t* __restrict__ m1_wb, const float* __restrict__ m1_g, const float* __restrict__ m1_b,
    const ushort_t* __restrict__ cur1,
    ushort_t* __restrict__ f01, const int G32)
{
    __shared__ __align__(16) ushort_t xlds[128 * 72];  // 18432 B
    __shared__ v4f      flds[128];       //  2048 B (total 20480 B -> 8 blk/CU)

    const int b = blockIdx.x;
    if (b < G32)
        sa_body<32>(b, src_xyz, dst_xyz, idx1, empty1, p1_w, p1_g, p1_b,
                    m1_wb, m1_g, m1_b, cur1, f01, 128, xlds, flds);
    else
        sa_body<16>(b - G32, src_xyz, dst_xyz, idx0, empty0, p0_w, p0_g, p0_b,
                    m0_wb, m0_g, m0_b, cur0, f01, 0, xlds, flds);
}

// ---------------------------------------------------------------------------
// Kernel 4: out[m][o] = relu(bn(f01[m] . out_w[o])) via MFMA.
// 32 rows/block (2 groups of 16), 4 waves split the 256 output cols, K=256.
// SWAPPED operands: acc = mfma(w, f01) -> C^T: row=(quad,reg)=n, col=lane=m.
// ---------------------------------------------------------------------------
__global__ __launch_bounds__(256) void out_kernel(
    const ushort_t* __restrict__ f01,     // (M,256) bf16
    const ushort_t* __restrict__ out_wb,  // (256,256) bf16
    const float*    __restrict__ out_g,
    const float*    __restrict__ out_b,
    float*          __restrict__ out)     // (M,256) f32
{
    const int tid  = threadIdx.x;
    const int lane = tid & 63;
    const int wid  = tid >> 6;
    const int col  = lane & 15;
    const int quad = lane >> 4;
    const int m0   = blockIdx.x * 32;

    v8s afrag[2][8];                     // [row-group][kf]
    #pragma unroll
    for (int rg = 0; rg < 2; ++rg)
        #pragma unroll
        for (int kf = 0; kf < 8; ++kf)
            afrag[rg][kf] = *(const v8s*)(
                f01 + (size_t)(m0 + rg * 16 + col) * 256 + kf * 32 + quad * 8);

    v4f acc[2][4];
    #pragma unroll
    for (int rg = 0; rg < 2; ++rg)
        #pragma unroll
        for (int c = 0; c < 4; ++c) acc[rg][c] = (v4f)0.0f;

    #pragma unroll
    for (int kf = 0; kf < 8; ++kf) {
        #pragma unroll
        for (int c = 0; c < 4; ++c) {
            const int n = (wid * 4 + c) * 16 + col;   // operand outer (lane&15)
            const v8s b = *(const v8s*)(out_wb + (size_t)n * 256 + kf * 32 + quad * 8);
            acc[0][c] = __builtin_amdgcn_mfma_f32_16x16x32_bf16(b, afrag[0][kf], acc[0][c], 0, 0, 0);
            acc[1][c] = __builtin_amdgcn_mfma_f32_16x16x32_bf16(b, afrag[1][kf], acc[1][c], 0, 0, 0);
        }
    }

    #pragma unroll
    for (int c = 0; c < 4; ++c) {
        const int nb = (wid * 4 + c) * 16 + quad * 4;       // 4 consecutive n
        const v4f og4 = *(const v4f*)(out_g + nb);
        const v4f ob4 = *(const v4f*)(out_b + nb);
        #pragma unroll
        for (int rg = 0; rg < 2; ++rg) {
            v4f y;
            #pragma unroll
            for (int r = 0; r < 4; ++r)
                y[r] = fmaxf(fmaf(acc[rg][c][r], og4[r] * BN_SCALE, ob4[r]), 0.0f);
            *(v4f*)(out + (size_t)(m0 + rg * 16 + col) * 256 + nb) = y;
        }
    }
}

// ---------------------------------------------------------------------------
extern "C" void kernel_launch(void* const* d_in, const int* in_sizes, int n_in,
                              void* d_out, int out_size, void* d_ws, size_t ws_size,
                              hipStream_t stream)
{
    const float* src_xyz   = (const float*)d_in[0];
    const float* src_feats = (const float*)d_in[1];
    const float* dst_xyz   = (const float*)d_in[2];
    const int*   idx0      = (const int*)d_in[3];
    const int*   idx1      = (const int*)d_in[4];
    const int*   empty0    = (const int*)d_in[5];
    const int*   empty1    = (const int*)d_in[6];
    const float* fc0_w     = (const float*)d_in[7];
    const float* fc0_b     = (const float*)d_in[8];
    const float* p0_w      = (const float*)d_in[9];
    const float* p0_g      = (const float*)d_in[10];
    const float* p0_b      = (const float*)d_in[11];
    const float* m0_w      = (const float*)d_in[12];
    const float* m0_g      = (const float*)d_in[13];
    const float* m0_b      = (const float*)d_in[14];
    const float* fc1_w     = (const float*)d_in[15];
    const float* fc1_b     = (const float*)d_in[16];
    const float* p1_w      = (const float*)d_in[17];
    const float* p1_g      = (const float*)d_in[18];
    const float* p1_b      = (const float*)d_in[19];
    const float* m1_w      = (const float*)d_in[20];
    const float* m1_g      = (const float*)d_in[21];
    const float* m1_b      = (const float*)d_in[22];
    const float* out_w     = (const float*)d_in[23];
    const float* out_g     = (const float*)d_in[24];
    const float* out_b     = (const float*)d_in[25];

    const int N = in_sizes[0] / 3;   // 65536
    const int M = in_sizes[2] / 3;   // 16384

    // ws layout: cur0 | cur1 (N*64 bf16) | f01 (M*256 bf16) | out_wb | m0_wb | m1_wb
    ushort_t* cur0   = (ushort_t*)d_ws;
    ushort_t* cur1   = cur0 + (size_t)N * 64;
    ushort_t* f01    = cur1 + (size_t)N * 64;
    ushort_t* out_wb = f01 + (size_t)M * 256;
    ushort_t* m0_wb  = out_wb + 256 * 256;
    ushort_t* m1_wb  = m0_wb + 128 * 64;

    const int G32 = M / 4;   // sa32: MB=4
    const int G16 = M / 8;   // sa16: MB=8
    const int CURB = N / 128;

    cur_conv_kernel<<<CURB + 80, 256, 0, stream>>>(
        src_feats, fc0_w, fc0_b, fc1_w, fc1_b, cur0, cur1,
        out_w, out_wb, m0_w, m0_wb, m1_w, m1_wb, CURB);
    sa_fused_kernel<<<G32 + G16, 256, 0, stream>>>(
        src_xyz, dst_xyz,
        idx0, empty0, p0_w, p0_g, p0_b, m0_wb, m0_g, m0_b, cur0,
        idx1, empty1, p1_w, p1_g, p1_b, m1_wb, m1_g, m1_b, cur1,
        f01, G32);
    out_kernel<<<M / 32, 256, 0, stream>>>(f01, out_wb, out_g, out_b,
                                           (float*)d_out);
}

// Round 10
// 179.679 us; speedup vs baseline: 1.0189x; 1.0189x over previous
//
#include <hip/hip_runtime.h>
#include <hip/hip_bf16.h>

typedef unsigned short ushort_t;
typedef unsigned int uint_t;
typedef __attribute__((ext_vector_type(8))) short v8s;   // 8 x bf16 (4 VGPRs)
typedef __attribute__((ext_vector_type(4))) float v4f;   // MFMA accumulator / float4

#define BN_SCALE 0.9999950000374997f

__device__ __forceinline__ ushort_t f2bf(float f) {
    union { uint_t i; float f; } v;
    v.f = f;
    uint_t b = v.i;
    b += 0x7fffu + ((b >> 16) & 1u);   // RNE
    return (ushort_t)(b >> 16);
}

// packed bf16 convert: v_cvt_pk_bf16_f32 (RNE). Low ushort = first arg.
__device__ __forceinline__ uint_t pkbf(float a, float b) {
    union { __hip_bfloat162 h2; uint_t u; } t;
    float2 f; f.x = a; f.y = b;
    t.h2 = __float22bfloat162_rn(f);
    return t.u;
}

// 8 x f32 -> v8s via 4 cvt_pk
__device__ __forceinline__ v8s cvt8f(const float* __restrict__ p) {
    const v4f a = *(const v4f*)p;
    const v4f b = *(const v4f*)(p + 4);
    union { uint4 q; v8s s; } r;
    r.q = make_uint4(pkbf(a[0], a[1]), pkbf(a[2], a[3]),
                     pkbf(b[0], b[1]), pkbf(b[2], b[3]));
    return r.s;
}

// ---------------------------------------------------------------------------
// Kernel 1: cur{0,1}[n][d] = src_feats[n] . fc{0,1}_w[d] + fc{0,1}_b[d]
// Pure-MFMA GEMM; fc weights converted in-register from f32 (cvt8f, cheap).
// 128 rows/block (2 groups of 64), weights loaded once per block.
// SWAPPED operands: acc = mfma(w, feat) -> C^T: row=(quad,reg)=d, col=lane=n.
// Blocks [CURB, CURB+80): folded weight-conversion (out_w/m0_w/m1_w f32->bf16)
// ---------------------------------------------------------------------------
__global__ __launch_bounds__(256) void cur_conv_kernel(
    const float* __restrict__ src_feats,                     // (N,64) f32
    const float* __restrict__ fc0_w, const float* __restrict__ fc0_b,
    const float* __restrict__ fc1_w, const float* __restrict__ fc1_b,
    ushort_t* __restrict__ cur0, ushort_t* __restrict__ cur1,
    const float* __restrict__ out_w, ushort_t* __restrict__ out_wb,
    const float* __restrict__ m0_w,  ushort_t* __restrict__ m0_wb,
    const float* __restrict__ m1_w,  ushort_t* __restrict__ m1_wb,
    const int CURB)
{
    if (blockIdx.x >= CURB) {
        // ---- weight conversion tail: 80 blocks ----
        const int b = blockIdx.x - CURB;
        const float* src;
        ushort_t* dst;
        int base;
        if (b < 64)      { src = out_w; dst = out_wb; base = b; }
        else if (b < 72) { src = m0_w;  dst = m0_wb;  base = b - 64; }
        else             { src = m1_w;  dst = m1_wb;  base = b - 72; }
        const int i = (base * 256 + threadIdx.x) * 4;
        const v4f v = *(const v4f*)(src + i);
        *(uint2*)(dst + i) = make_uint2(pkbf(v[0], v[1]), pkbf(v[2], v[3]));
        return;
    }

    const int tid  = threadIdx.x;
    const int lane = tid & 63;
    const int wid  = tid >> 6;
    const int col  = lane & 15;
    const int quad = lane >> 4;
    const int row0 = blockIdx.x * 128 + wid * 16;

    // ---- weight fragments (cvt from f32) + bias4: once, reused both groups ----
    v8s bfrag[8][2];
    v4f bias4[8];
    #pragma unroll
    for (int ct = 0; ct < 8; ++ct) {
        const int d = (ct & 3) * 16 + col;            // operand outer (lane&15)
        const float* w = (ct < 4 ? fc0_w : fc1_w) + d * 64;
        bias4[ct] = *(const v4f*)((ct < 4 ? fc0_b : fc1_b) + (ct & 3) * 16 + quad * 4);
        #pragma unroll
        for (int kf = 0; kf < 2; ++kf)
            bfrag[ct][kf] = cvt8f(w + kf * 32 + quad * 8);
    }

    #pragma unroll
    for (int g = 0; g < 2; ++g) {
        const int rows = row0 + g * 64;
        const int n    = rows + col;

        v8s afrag[2];
        #pragma unroll
        for (int kf = 0; kf < 2; ++kf)
            afrag[kf] = cvt8f(src_feats + (size_t)n * 64 + kf * 32 + quad * 8);

        v4f acc[8];
        #pragma unroll
        for (int ct = 0; ct < 8; ++ct)
            acc[ct] = bias4[ct];                      // bias[d], d=(ct&3)*16+quad*4+r

        #pragma unroll
        for (int kf = 0; kf < 2; ++kf)
            #pragma unroll
            for (int ct = 0; ct < 8; ++ct)
                acc[ct] = __builtin_amdgcn_mfma_f32_16x16x32_bf16(
                    bfrag[ct][kf], afrag[kf], acc[ct], 0, 0, 0);   // swapped: C^T

        #pragma unroll
        for (int ct = 0; ct < 8; ++ct) {
            ushort_t* dst = (ct < 4) ? cur0 : cur1;
            const uint2 u = make_uint2(pkbf(acc[ct][0], acc[ct][1]),
                                       pkbf(acc[ct][2], acc[ct][3]));
            *(uint2*)(dst + (size_t)n * 64 + (ct & 3) * 16 + quad * 4) = u;
        }
    }
}

// ---------------------------------------------------------------------------
// SA layer body (verified PASS x5: R0/R3/R5/R6/R8 structure). 128 pairs/block.
// Phase A: paired-d SCALAR math, dd2 layout — all restructures (R1/R2/R7/R9)
//   failed verification; this layout is the verified local optimum.
// Phase B: per-wave col-split (2 cts/wave) over MB independent m's.
// ---------------------------------------------------------------------------
template <int S>
__device__ __forceinline__ void sa_body(
    const int bid,
    const float* __restrict__ src_xyz,   // (N,3) f32
    const float* __restrict__ dst_xyz,   // (M,3) f32
    const int*   __restrict__ idx,       // (M,S)
    const int*   __restrict__ empty,     // (M,)
    const float* __restrict__ p_w,       // (64,6)
    const float* __restrict__ p_g,
    const float* __restrict__ p_b,
    const ushort_t* __restrict__ m_wb,   // (128,64) bf16 (pre-converted)
    const float* __restrict__ m_g,
    const float* __restrict__ m_b,
    const ushort_t* __restrict__ cur,    // (N,64) bf16
    ushort_t*    __restrict__ f01,       // (M,256) bf16
    const int layer_off,
    ushort_t* xlds,                      // [128 * 72]
    v4f*      flds)                      // [128]
{
    constexpr int PAIRS = 128;
    constexpr int MB = PAIRS / S;        // 4 (S=32) or 8 (S=16)
    constexpr int XP = 72;               // padded row stride (ushorts), 144 B
    constexpr int T  = S / 4;            // pairs per (wave, mi) in phase A

    const int tid  = threadIdx.x;
    const int lane = tid & 63;
    const int wid  = tid >> 6;           // 0..3
    const int m0   = bid * MB;

    // ---- prologue 1: cur rows -> xlds (coalesced, in-place with x) ----
    {
        const int p  = tid >> 1;         // pair 0..127
        const int hf = tid & 1;
        const int m  = m0 + p / S;
        const int i  = idx[(size_t)m * S + (p & (S - 1))];
        const uint_t* crow = (const uint_t*)(cur + (size_t)i * 64) + hf * 16;
        const uint4 c0 = *(const uint4*)(crow + 0);
        const uint4 c1 = *(const uint4*)(crow + 4);
        const uint4 c2 = *(const uint4*)(crow + 8);
        const uint4 c3 = *(const uint4*)(crow + 12);
        uint_t* drow = (uint_t*)(xlds + p * XP) + hf * 16;
        *(uint4*)(drow + 0)  = c0;
        *(uint4*)(drow + 4)  = c1;
        *(uint4*)(drow + 8)  = c2;
        *(uint4*)(drow + 12) = c3;
    }
    // ---- prologue 2: relative coords -> flds ----
    if (tid < PAIRS) {
        const int p = tid;
        const int m = m0 + p / S;
        const int i = idx[(size_t)m * S + (p & (S - 1))];
        const float dx = dst_xyz[m * 3 + 0];
        const float dy = dst_xyz[m * 3 + 1];
        const float dz = dst_xyz[m * 3 + 2];
        v4f r;
        r[0] = src_xyz[i * 3 + 0] - dx;
        r[1] = src_xyz[i * 3 + 1] - dy;
        r[2] = src_xyz[i * 3 + 2] - dz;
        r[3] = 0.0f;
        flds[p] = r;
    }

    // ---- per-lane paired-d constants (d = dd, dd+1) ----
    const int dd = (lane & 31) * 2;
    const int psub = lane >> 5;          // 0/1: which pair of the iter
    const float pgA = p_g[dd] * BN_SCALE;
    const float pgB = p_g[dd + 1] * BN_SCALE;
    const float pbA = p_b[dd];
    const float pbB = p_b[dd + 1];
    const float pwA0 = p_w[dd * 6 + 0] * pgA;
    const float pwA1 = p_w[dd * 6 + 1] * pgA;
    const float pwA2 = p_w[dd * 6 + 2] * pgA;
    const float pdA0 = p_w[dd * 6 + 3] * pgA;
    const float pdA1 = p_w[dd * 6 + 4] * pgA;
    const float pdA2 = p_w[dd * 6 + 5] * pgA;
    const float pwB0 = p_w[dd * 6 + 6] * pgB;
    const float pwB1 = p_w[dd * 6 + 7] * pgB;
    const float pwB2 = p_w[dd * 6 + 8] * pgB;
    const float pdB0 = p_w[dd * 6 + 9] * pgB;
    const float pdB1 = p_w[dd * 6 + 10] * pgB;
    const float pdB2 = p_w[dd * 6 + 11] * pgB;

    __syncthreads();

    // ================= phase A: paired-d, pure LDS + VALU =================
    const int tbase = wid * T;
    #pragma unroll
    for (int mi = 0; mi < MB; ++mi) {
        const int m = m0 + mi;                        // uniform
        const int em = empty[m];                      // uniform -> s_cbranch
        if (em) {
            // x must be exactly 0 for empty dst points (same word coverage)
            #pragma unroll
            for (int it = 0; it < T / 2; ++it) {
                const int p = mi * S + tbase + it * 2 + psub;
                *(uint_t*)(xlds + p * XP + dd) = 0u;
            }
        } else {
            const float dx = dst_xyz[m * 3 + 0];      // uniform loads
            const float dy = dst_xyz[m * 3 + 1];
            const float dz = dst_xyz[m * 3 + 2];
            const float vbA = fmaf(pdA0, dx, fmaf(pdA1, dy, fmaf(pdA2, dz, pbA)));
            const float vbB = fmaf(pdB0, dx, fmaf(pdB1, dy, fmaf(pdB2, dz, pbB)));

            #pragma unroll
            for (int it = 0; it < T / 2; ++it) {
                const int p = mi * S + tbase + it * 2 + psub;
                const v4f r = flds[p];                    // 2-addr broadcast b128
                const uint_t cu = *(const uint_t*)(xlds + p * XP + dd);   // b32
                const float c0 = __uint_as_float(cu << 16);
                const float c1 = __uint_as_float(cu & 0xffff0000u);

                const float v0 = fmaf(pwA0, r[0], fmaf(pwA1, r[1], fmaf(pwA2, r[2], vbA)));
                const float v1 = fmaf(pwB0, r[0], fmaf(pwB1, r[1], fmaf(pwB2, r[2], vbB)));
                const float rc0 = __builtin_amdgcn_rcpf(1.0f + __expf(-v0));
                const float rc1 = __builtin_amdgcn_rcpf(1.0f + __expf(-v1));
                const float x0 = fmaf(v0, rc0, c0);
                const float x1 = fmaf(v1, rc1, c1);

                *(uint_t*)(xlds + p * XP + dd) = pkbf(x0, x1);  // b32 in place
            }
        }
    }

    // ---- phase-B per-wave constants (direct bf16 loads, no cvt) ----
    const int col  = lane & 15;
    const int quad = lane >> 4;
    v8s bfrag[2][2];                     // [ct][kf]
    float mgv[2], mbv[2];
    #pragma unroll
    for (int c = 0; c < 2; ++c) {
        const int h = (wid * 2 + c) * 16 + col;
        #pragma unroll
        for (int kf = 0; kf < 2; ++kf)
            bfrag[c][kf] = *(const v8s*)(m_wb + h * 64 + kf * 32 + quad * 8);
        mgv[c] = m_g[h] * BN_SCALE;
        mbv[c] = m_b[h];
    }

    __syncthreads();

    // ================= phase B: MB independent m's per wave =================
    #pragma unroll
    for (int mi = 0; mi < MB; ++mi) {
        const int m = m0 + mi;
        v4f acc[S / 16][2];
        #pragma unroll
        for (int rt = 0; rt < S / 16; ++rt)
            #pragma unroll
            for (int c = 0; c < 2; ++c)
                acc[rt][c] = (v4f)0.0f;

        #pragma unroll
        for (int rt = 0; rt < S / 16; ++rt) {
            #pragma unroll
            for (int kf = 0; kf < 2; ++kf) {
                const v8s afrag = *(const v8s*)(
                    xlds + ((mi * S + rt * 16 + col)) * XP + kf * 32 + quad * 8);
                acc[rt][0] = __builtin_amdgcn_mfma_f32_16x16x32_bf16(
                    afrag, bfrag[0][kf], acc[rt][0], 0, 0, 0);
                acc[rt][1] = __builtin_amdgcn_mfma_f32_16x16x32_bf16(
                    afrag, bfrag[1][kf], acc[rt][1], 0, 0, 0);
            }
        }

        // epilogue: bn, relu, max over s (C/D layout: col=lane&15, row=quad*4+r)
        float vmax0 = 0.0f, vmax1 = 0.0f;
        #pragma unroll
        for (int c = 0; c < 2; ++c) {
            float vm = 0.0f;   // relu(y)>=0, so 0 is a valid identity
            #pragma unroll
            for (int rt = 0; rt < S / 16; ++rt)
                #pragma unroll
                for (int r = 0; r < 4; ++r) {
                    const float y = fmaf(acc[rt][c][r], mgv[c], mbv[c]);
                    vm = fmaxf(vm, y);
                }
            vm = fmaxf(vm, __shfl_xor(vm, 16));
            vm = fmaxf(vm, __shfl_xor(vm, 32));
            if (c == 0) vmax0 = vm; else vmax1 = vm;
        }
        if (lane < 32) {
            const int c = lane >> 4;
            const float val = (c == 0) ? vmax0 : vmax1;
            f01[m * 256 + layer_off + (wid * 2 + c) * 16 + (lane & 15)] = f2bf(val);
        }
    }
}

// ---------------------------------------------------------------------------
// Kernel 2: fused SA layers. Blocks [0, G32) run layer 1 (S=32), blocks
// [G32, G32+G16) run layer 0 (S=16).
// ---------------------------------------------------------------------------
__global__ __launch_bounds__(256, 6) void sa_fused_kernel(
    const float* __restrict__ src_xyz, const float* __restrict__ dst_xyz,
    const int* __restrict__ idx0, const int* __restrict__ empty0,
    const float* __restrict__ p0_w, const float* __restrict__ p0_g, const float* __restrict__ p0_b,
    const ushort_t* __restrict__ m0_wb, const float* __restrict__ m0_g, const float* __restrict__ m0_b,
    const ushort_t* __restrict__ cur0,
    const int* __restrict__ idx1, const int* __restrict__ empty1,
    const float* __restrict__ p1_w, const float* __restrict__ p1_g, const float* __restrict__ p1_b,
    const ushort_t* __restrict__ m1_wb, const float* __restrict__ m1_g, const float* __restrict__ m1_b,
    const ushort_t* __restrict__ cur1,
    ushort_t* __restrict__ f01, const int G32)
{
    __shared__ __align__(16) ushort_t xlds[128 * 72];  // 18432 B
    __shared__ v4f      flds[128];       //  2048 B (total 20480 B -> 8 blk/CU)

    const int b = blockIdx.x;
    if (b < G32)
        sa_body<32>(b, src_xyz, dst_xyz, idx1, empty1, p1_w, p1_g, p1_b,
                    m1_wb, m1_g, m1_b, cur1, f01, 128, xlds, flds);
    else
        sa_body<16>(b - G32, src_xyz, dst_xyz, idx0, empty0, p0_w, p0_g, p0_b,
                    m0_wb, m0_g, m0_b, cur0, f01, 0, xlds, flds);
}

// ---------------------------------------------------------------------------
// Kernel 4: out[m][o] = relu(bn(f01[m] . out_w[o])) via MFMA.
// 32 rows/block (2 groups of 16), 4 waves split the 256 output cols, K=256.
// SWAPPED operands: acc = mfma(w, f01) -> C^T: row=(quad,reg)=n, col=lane=m.
// ---------------------------------------------------------------------------
__global__ __launch_bounds__(256) void out_kernel(
    const ushort_t* __restrict__ f01,     // (M,256) bf16
    const ushort_t* __restrict__ out_wb,  // (256,256) bf16
    const float*    __restrict__ out_g,
    const float*    __restrict__ out_b,
    float*          __restrict__ out)     // (M,256) f32
{
    const int tid  = threadIdx.x;
    const int lane = tid & 63;
    const int wid  = tid >> 6;
    const int col  = lane & 15;
    const int quad = lane >> 4;
    const int m0   = blockIdx.x * 32;

    v8s afrag[2][8];                     // [row-group][kf]
    #pragma unroll
    for (int rg = 0; rg < 2; ++rg)
        #pragma unroll
        for (int kf = 0; kf < 8; ++kf)
            afrag[rg][kf] = *(const v8s*)(
                f01 + (size_t)(m0 + rg * 16 + col) * 256 + kf * 32 + quad * 8);

    v4f acc[2][4];
    #pragma unroll
    for (int rg = 0; rg < 2; ++rg)
        #pragma unroll
        for (int c = 0; c < 4; ++c) acc[rg][c] = (v4f)0.0f;

    #pragma unroll
    for (int kf = 0; kf < 8; ++kf) {
        #pragma unroll
        for (int c = 0; c < 4; ++c) {
            const int n = (wid * 4 + c) * 16 + col;   // operand outer (lane&15)
            const v8s b = *(const v8s*)(out_wb + (size_t)n * 256 + kf * 32 + quad * 8);
            acc[0][c] = __builtin_amdgcn_mfma_f32_16x16x32_bf16(b, afrag[0][kf], acc[0][c], 0, 0, 0);
            acc[1][c] = __builtin_amdgcn_mfma_f32_16x16x32_bf16(b, afrag[1][kf], acc[1][c], 0, 0, 0);
        }
    }

    #pragma unroll
    for (int c = 0; c < 4; ++c) {
        const int nb = (wid * 4 + c) * 16 + quad * 4;       // 4 consecutive n
        const v4f og4 = *(const v4f*)(out_g + nb);
        const v4f ob4 = *(const v4f*)(out_b + nb);
        #pragma unroll
        for (int rg = 0; rg < 2; ++rg) {
            v4f y;
            #pragma unroll
            for (int r = 0; r < 4; ++r)
                y[r] = fmaxf(fmaf(acc[rg][c][r], og4[r] * BN_SCALE, ob4[r]), 0.0f);
            *(v4f*)(out + (size_t)(m0 + rg * 16 + col) * 256 + nb) = y;
        }
    }
}

// ---------------------------------------------------------------------------
extern "C" void kernel_launch(void* const* d_in, const int* in_sizes, int n_in,
                              void* d_out, int out_size, void* d_ws, size_t ws_size,
                              hipStream_t stream)
{
    const float* src_xyz   = (const float*)d_in[0];
    const float* src_feats = (const float*)d_in[1];
    const float* dst_xyz   = (const float*)d_in[2];
    const int*   idx0      = (const int*)d_in[3];
    const int*   idx1      = (const int*)d_in[4];
    const int*   empty0    = (const int*)d_in[5];
    const int*   empty1    = (const int*)d_in[6];
    const float* fc0_w     = (const float*)d_in[7];
    const float* fc0_b     = (const float*)d_in[8];
    const float* p0_w      = (const float*)d_in[9];
    const float* p0_g      = (const float*)d_in[10];
    const float* p0_b      = (const float*)d_in[11];
    const float* m0_w      = (const float*)d_in[12];
    const float* m0_g      = (const float*)d_in[13];
    const float* m0_b      = (const float*)d_in[14];
    const float* fc1_w     = (const float*)d_in[15];
    const float* fc1_b     = (const float*)d_in[16];
    const float* p1_w      = (const float*)d_in[17];
    const float* p1_g      = (const float*)d_in[18];
    const float* p1_b      = (const float*)d_in[19];
    const float* m1_w      = (const float*)d_in[20];
    const float* m1_g      = (const float*)d_in[21];
    const float* m1_b      = (const float*)d_in[22];
    const float* out_w     = (const float*)d_in[23];
    const float* out_g     = (const float*)d_in[24];
    const float* out_b     = (const float*)d_in[25];

    const int N = in_sizes[0] / 3;   // 65536
    const int M = in_sizes[2] / 3;   // 16384

    // ws layout: cur0 | cur1 (N*64 bf16) | f01 (M*256 bf16) | out_wb | m0_wb | m1_wb
    ushort_t* cur0   = (ushort_t*)d_ws;
    ushort_t* cur1   = cur0 + (size_t)N * 64;
    ushort_t* f01    = cur1 + (size_t)N * 64;
    ushort_t* out_wb = f01 + (size_t)M * 256;
    ushort_t* m0_wb  = out_wb + 256 * 256;
    ushort_t* m1_wb  = m0_wb + 128 * 64;

    const int G32 = M / 4;   // sa32: MB=4
    const int G16 = M / 8;   // sa16: MB=8
    const int CURB = N / 128;

    cur_conv_kernel<<<CURB + 80, 256, 0, stream>>>(
        src_feats, fc0_w, fc0_b, fc1_w, fc1_b, cur0, cur1,
        out_w, out_wb, m0_w, m0_wb, m1_w, m1_wb, CURB);
    sa_fused_kernel<<<G32 + G16, 256, 0, stream>>>(
        src_xyz, dst_xyz,
        idx0, empty0, p0_w, p0_g, p0_b, m0_wb, m0_g, m0_b, cur0,
        idx1, empty1, p1_w, p1_g, p1_b, m1_wb, m1_g, m1_b, cur1,
        f01, G32);
    out_kernel<<<M / 32, 256, 0, stream>>>(f01, out_wb, out_g, out_b,
                                           (float*)d_out);
}